// Round 11
// baseline (330.588 us; speedup 1.0000x reference)
//
#include <hip/hip_runtime.h>

// Problem constants
#define D_    2048
#define OUT_  2048
#define E_    8
#define R_    16
#define KX    2176          // D_ + E_*R_  (K-extended GEMM depth)
#define M_    16384         // B*S tokens
#define SCALING_F 2.0f      // ALPHA / R = 32/16

typedef unsigned short ushort_t;
typedef unsigned short ushort8 __attribute__((ext_vector_type(8)));
typedef __bf16 bf16x8 __attribute__((ext_vector_type(8)));
typedef float f32x4 __attribute__((ext_vector_type(4)));

__device__ __forceinline__ ushort_t f2bf(float f) {
  unsigned u = __float_as_uint(f);
  u += 0x7FFFu + ((u >> 16) & 1u);   // round-to-nearest-even
  return (ushort_t)(u >> 16);
}

#define GLOAD16(gp, lp)                                                        \
  __builtin_amdgcn_global_load_lds(                                            \
      (const __attribute__((address_space(1))) void*)(gp),                     \
      (__attribute__((address_space(3))) void*)(lp), 16, 0, 0)

// -------- W_ext + A_ext prep (fused): wext[OUT_][KX], aext[128][D_] bf16 ----
__global__ __launch_bounds__(256) void wprep_all_kernel(
    const float* __restrict__ W, const float* __restrict__ Bw,
    const float* __restrict__ A,
    ushort_t* __restrict__ wext, ushort_t* __restrict__ aext)
{
  const int bid = blockIdx.x;
  const int t = threadIdx.x;
  if (bid < OUT_) {
    const int o = bid;
    const float* wr = W + (size_t)o * D_ + t * 8;
    float4 v0 = *(const float4*)wr;
    float4 v1 = *(const float4*)(wr + 4);
    ushort8 wb;
    wb[0] = f2bf(v0.x); wb[1] = f2bf(v0.y); wb[2] = f2bf(v0.z); wb[3] = f2bf(v0.w);
    wb[4] = f2bf(v1.x); wb[5] = f2bf(v1.y); wb[6] = f2bf(v1.z); wb[7] = f2bf(v1.w);
    *(ushort8*)(wext + (size_t)o * KX + t * 8) = wb;
    if (t < E_ * R_) {
      const int e = t >> 4, r = t & 15;
      wext[(size_t)o * KX + D_ + t] = f2bf(Bw[((size_t)e * OUT_ + o) * R_ + r]);
    }
  } else {
    const size_t i = ((size_t)(bid - OUT_) * 256 + t) * 8;
    float4 v0 = *(const float4*)(A + i);
    float4 v1 = *(const float4*)(A + i + 4);
    ushort8 b;
    b[0] = f2bf(v0.x); b[1] = f2bf(v0.y); b[2] = f2bf(v0.z); b[3] = f2bf(v0.w);
    b[4] = f2bf(v1.x); b[5] = f2bf(v1.y); b[6] = f2bf(v1.z); b[7] = f2bf(v1.w);
    *(ushort8*)(aext + i) = b;
  }
}

// ---- FUSED router + h GEMM + x convert, BARRIER-FREE main loop -------------
// 512 blocks x 32 rows, 256 thr (4 waves: wr=w>>1 row-half, wc=w&1 col-half).
// Fragment-owner = data-owner: thread (wr,lr,lg) loads x fp32 for exactly its
// af fragment (row wr*16+lr, cols kk*32+lg*8), cvt -> bf16 (bit-identical to
// the r6/r10 LDS path), wc==0 stores the xext-core slice. B-fragments read
// DIRECTLY from global Ae (512 KB, L2-hot) — no LDS, no barriers in the loop.
// Logits: wc0 accumulates experts 0-3, wc1 experts 4-7 (fp32 partials over
// this thread's 16 cols/tile); end: fp64 shfl tree over lg + LDS combine +
// first-max argmax. MFMA inputs byte-identical to r10 => same h, same absmax.
#define HG_NKT (D_ / 64)     // 32 K-tiles

__global__ __launch_bounds__(256) void hrouter2_kernel(
    const float* __restrict__ x,       // [M_][D_] fp32
    const float* __restrict__ rW,      // [E_][D_] fp32
    const ushort_t* __restrict__ Ae,   // [128][D_] bf16
    ushort_t* __restrict__ xext)       // writes all KX cols
{
  __shared__ double lsum[2][2][16][4];
  __shared__ int esel[32];

  const int t = threadIdx.x;
  const int lane = t & 63, w = t >> 6;
  const int wr = w >> 1, wc = w & 1;          // wave tile 16 rows x 64 cols
  const int lr = lane & 15, lg = lane >> 4;

  const int bm = blockIdx.x;                   // 512 blocks x 32 rows
  const size_t row0 = (size_t)bm * 32;
  const size_t arow = row0 + wr * 16 + lr;     // this thread's x/A-frag row

  float la[4] = {0.f, 0.f, 0.f, 0.f};          // experts wc*4 .. wc*4+3
  f32x4 acc[4] = {};

  const float* xrow = x + arow * D_;
  ushort_t* xsrow = xext + arow * KX;

  for (int T = 0; T < HG_NKT; ++T) {
    const int c0 = T * 64 + lg * 8;            // col base, kk adds 32
    bf16x8 af[2];
    #pragma unroll
    for (int kk = 0; kk < 2; ++kk) {
      const float* xp = xrow + c0 + kk * 32;
      float4 a = *(const float4*)xp;
      float4 b = *(const float4*)(xp + 4);
      union { ushort8 u; bf16x8 h; } cv;
      cv.u[0] = f2bf(a.x); cv.u[1] = f2bf(a.y); cv.u[2] = f2bf(a.z); cv.u[3] = f2bf(a.w);
      cv.u[4] = f2bf(b.x); cv.u[5] = f2bf(b.y); cv.u[6] = f2bf(b.z); cv.u[7] = f2bf(b.w);
      af[kk] = cv.h;
      if (wc == 0)
        *(ushort8*)(xsrow + c0 + kk * 32) = cv.u;   // xext core slice
      // logit partials for this thread's 8 cols, experts wc*4..+4
      #pragma unroll
      for (int j = 0; j < 4; ++j) {
        const float* wp = rW + (size_t)(wc * 4 + j) * D_ + c0 + kk * 32;
        float4 w0 = *(const float4*)wp;
        float4 w1 = *(const float4*)(wp + 4);
        la[j] += a.x * w0.x + a.y * w0.y + a.z * w0.z + a.w * w0.w
               + b.x * w1.x + b.y * w1.y + b.z * w1.z + b.w * w1.w;
      }
    }
    // B-frags straight from global Ae (L2-hot), same bytes as the LDS path
    #pragma unroll
    for (int nj = 0; nj < 4; ++nj) {
      const size_t Rc = wc * 64 + nj * 16 + lr;
      #pragma unroll
      for (int kk = 0; kk < 2; ++kk) {
        bf16x8 bfr = *(const bf16x8*)(Ae + Rc * D_ + c0 + kk * 32);
        acc[nj] = __builtin_amdgcn_mfma_f32_16x16x32_bf16(af[kk], bfr, acc[nj], 0, 0, 0);
      }
    }
  }

  // router finish: fp64 tree over lg lanes (xor 16, 32) -> LDS -> argmax
  {
    double s[4];
    #pragma unroll
    for (int j = 0; j < 4; ++j) s[j] = (double)la[j];
    #pragma unroll
    for (int off = 16; off <= 32; off <<= 1)
      #pragma unroll
      for (int j = 0; j < 4; ++j) s[j] += __shfl_xor(s[j], off, 64);
    if (lg == 0) {
      #pragma unroll
      for (int j = 0; j < 4; ++j) lsum[wr][wc][lr][j] = s[j];
    }
  }
  __syncthreads();
  if (wc == 0 && lg == 0) {
    double best = lsum[wr][0][lr][0]; int bi = 0;
    #pragma unroll
    for (int e = 1; e < E_; ++e) {
      double v = (e < 4) ? lsum[wr][0][lr][e] : lsum[wr][1][lr][e - 4];
      if (v > best) { best = v; bi = e; }      // first-max tie-break
    }
    esel[wr * 16 + lr] = bi;
  }
  __syncthreads();

  // masked epilogue: xext[row][D_+col] = (esel[row]==col>>4) ? bf16(2*h) : 0
  int er[4];
  #pragma unroll
  for (int rr = 0; rr < 4; ++rr)
    er[rr] = esel[wr * 16 + lg * 4 + rr];
  #pragma unroll
  for (int nj = 0; nj < 4; ++nj) {
    const int col = wc * 64 + nj * 16 + lr;
    const int ecol = wc * 4 + nj;              // col>>4, wave-uniform per nj
    #pragma unroll
    for (int rr = 0; rr < 4; ++rr) {
      const size_t row = row0 + wr * 16 + lg * 4 + rr;
      ushort_t v = (er[rr] == ecol) ? f2bf(acc[nj][rr] * SCALING_F) : (ushort_t)0;
      xext[row * KX + D_ + col] = v;
    }
  }
}

// ---------------- GEMM: 256x256, symmetric 8-phase / 2-K-tile schedule ------
// (byte-identical to round 10 — isolation)
#define NKT (KX / 64)        // 34 K-tiles
#define NITER (NKT / 2)      // 17 iterations
#define NSTG (NKT * 4)       // 136 half-tile stages

__global__ __launch_bounds__(512, 2) void gemm_kernel(
    const ushort_t* __restrict__ Ag,   // [M_][KX] bf16
    const ushort_t* __restrict__ Bg,   // [OUT_][KX] bf16
    const float* __restrict__ bias,
    float* __restrict__ C)
{
  __shared__ __attribute__((aligned(16))) char lds[131072];

  const int t = threadIdx.x;
  const int lane = t & 63, w = t >> 6;
  const int wm = w >> 2, wn = w & 3;          // 2x4 wave grid; wave tile 128x64
  const int lr = lane & 15, lg = lane >> 4;
  const int koff = (lr & 7) << 4;             // read-side swizzle XOR (bytes)

  // XCD-bijective blockIdx swizzle (512 % 8 == 0)
  const int swz = (blockIdx.x & 7) * 64 + (blockIdx.x >> 3);
  const int bm = swz >> 3, bn = swz & 7;

  const int sg_row = t >> 3;
  const int sg_slotx = (t & 7) ^ ((t >> 3) & 7);   // pre-swizzled source slot
  const size_t aRow0 = (size_t)bm * 256;
  const size_t bRow0 = (size_t)bn * 256;

  // stage half-tile s: tile TT=s>>2, j=s&3 (0,1 = A halves; 2,3 = B halves)
  auto stage = [&](int s) {
    if (s >= NSTG) return;
    const int TT = s >> 2, j = s & 3;
    const int isB = j >> 1, half = j & 1;
    const ushort_t* src = isB ? Bg : Ag;
    const size_t gr0 = (isB ? bRow0 : aRow0) + half * 128;
    char* dst = lds + (TT & 1) * 65536 + isB * 32768 + half * 16384;
    #pragma unroll
    for (int g = 0; g < 2; ++g) {
      const int r = g * 64 + sg_row;
      GLOAD16(src + (gr0 + r) * KX + TT * 64 + sg_slotx * 8,
              dst + g * 8192 + t * 16);
    }
  };

  f32x4 acc[8][4] = {};
  bf16x8 bq[4][2];

  // prologue: tile0 {A0,A1,B0,B1} + tile1 {B0,B1}; wait tile0 landed,
  // leaving tile1's B (4 loads) in flight. (tile1's A staged at iter0 p0/p1.)
  stage(0); stage(1); stage(2); stage(3);
  stage(6); stage(7);
  asm volatile("s_waitcnt vmcnt(4)" ::: "memory");
  __builtin_amdgcn_s_barrier();

  for (int ii = 0; ii < NITER; ++ii) {
    #pragma unroll
    for (int p = 0; p < 8; ++p) {
      const int q = p & 3;
      char* Ab = lds + ((2 * ii + (p >> 2)) & 1) * 65536;
      char* Bb = Ab + 32768;
      // --- ds-load register subtile ---
      bf16x8 aq[2][2];
      if (q == 0) {
        #pragma unroll
        for (int nj = 0; nj < 4; ++nj) {
          const int R = wn * 64 + nj * 16 + lr;
          #pragma unroll
          for (int kk = 0; kk < 2; ++kk)
            bq[nj][kk] = *(const bf16x8*)(Bb + R * 128 + ((kk * 64 + lg * 16) ^ koff));
        }
      }
      #pragma unroll
      for (int i = 0; i < 2; ++i) {
        const int R = wm * 128 + (q * 2 + i) * 16 + lr;
        #pragma unroll
        for (int kk = 0; kk < 2; ++kk)
          aq[i][kk] = *(const bf16x8*)(Ab + R * 128 + ((kk * 64 + lg * 16) ^ koff));
      }
      // --- one half-tile stage per phase ---
      switch (p) {
        case 0: stage(4 * (2 * ii + 1) + 0); break;
        case 1: stage(4 * (2 * ii + 1) + 1); break;
        case 2: stage(4 * (2 * ii + 2) + 2); break;
        case 3: stage(4 * (2 * ii + 2) + 3); break;
        case 4: stage(4 * (2 * ii + 2) + 0); break;
        case 5: stage(4 * (2 * ii + 2) + 1); break;
        case 6: stage(4 * (2 * ii + 3) + 2); break;
        case 7: stage(4 * (2 * ii + 3) + 3); break;
      }
      if (q == 0) asm volatile("s_waitcnt lgkmcnt(8)" ::: "memory");
      __builtin_amdgcn_s_barrier();
      asm volatile("s_waitcnt lgkmcnt(0)" ::: "memory");
      // --- MFMA cluster: one C-quadrant (2 m-frags x 4 n-frags) x K=64 ---
      __builtin_amdgcn_s_setprio(1);
      #pragma unroll
      for (int i = 0; i < 2; ++i)
        #pragma unroll
        for (int nj = 0; nj < 4; ++nj)
          #pragma unroll
          for (int kk = 0; kk < 2; ++kk)
            acc[q * 2 + i][nj] = __builtin_amdgcn_mfma_f32_16x16x32_bf16(
                aq[i][kk], bq[nj][kk], acc[q * 2 + i][nj], 0, 0, 0);
      __builtin_amdgcn_s_setprio(0);
      if (p == 3 || p == 7) {
        if (ii == NITER - 1) asm volatile("s_waitcnt vmcnt(0)" ::: "memory");
        else                 asm volatile("s_waitcnt vmcnt(4)" ::: "memory");
      }
      __builtin_amdgcn_s_barrier();
    }
  }

  // epilogue: C = acc + bias ; C/D layout col=lane&15, row=(lane>>4)*4+reg
  #pragma unroll
  for (int nj = 0; nj < 4; ++nj) {
    const int col = bn * 256 + wn * 64 + nj * 16 + lr;
    const float bv = bias[col];
    #pragma unroll
    for (int mi = 0; mi < 8; ++mi) {
      const int row0 = bm * 256 + wm * 128 + mi * 16 + lg * 4;
      #pragma unroll
      for (int rr = 0; rr < 4; ++rr)
        C[(size_t)(row0 + rr) * OUT_ + col] = acc[mi][nj][rr] + bv;
    }
  }
}

extern "C" void kernel_launch(void* const* d_in, const int* in_sizes, int n_in,
                              void* d_out, int out_size, void* d_ws, size_t ws_size,
                              hipStream_t stream) {
  const float* x  = (const float*)d_in[0];   // [4,4096,2048]
  const float* Wb = (const float*)d_in[1];   // [2048,2048]
  const float* bb = (const float*)d_in[2];   // [2048]
  const float* rW = (const float*)d_in[3];   // [8,2048]
  const float* A  = (const float*)d_in[4];   // [8,16,2048]
  const float* Bw = (const float*)d_in[5];   // [8,2048,16]
  float* out = (float*)d_out;                // [4,4096,2048] fp32

  ushort_t* xext = (ushort_t*)d_ws;                                   // M_ x KX bf16
  ushort_t* wext = (ushort_t*)((char*)d_ws + (size_t)M_ * KX * 2);    // OUT_ x KX bf16
  ushort_t* aext = (ushort_t*)((char*)d_ws + (size_t)M_ * KX * 2
                                           + (size_t)OUT_ * KX * 2);  // 128 x D_ bf16

  wprep_all_kernel<<<OUT_ + (E_ * R_ * D_) / (256 * 8), 256, 0, stream>>>(Wb, Bw, A, wext, aext);
  hrouter2_kernel<<<M_ / 32, 256, 0, stream>>>(x, rW, aext, xext);
  gemm_kernel<<<(M_ / 256) * (OUT_ / 256), 512, 0, stream>>>(xext, wext, bb, out);
}

// Round 12
// 246.773 us; speedup vs baseline: 1.3396x; 1.3396x over previous
//
#include <hip/hip_runtime.h>

// Problem constants
#define D_    2048
#define OUT_  2048
#define E_    8
#define R_    16
#define KX    2176          // D_ + E_*R_  (K-extended GEMM depth)
#define M_    16384         // B*S tokens
#define SCALING_F 2.0f      // ALPHA / R = 32/16

typedef unsigned short ushort_t;
typedef unsigned short ushort8 __attribute__((ext_vector_type(8)));
typedef __bf16 bf16x8 __attribute__((ext_vector_type(8)));
typedef float f32x4 __attribute__((ext_vector_type(4)));

__device__ __forceinline__ ushort_t f2bf(float f) {
  unsigned u = __float_as_uint(f);
  u += 0x7FFFu + ((u >> 16) & 1u);   // round-to-nearest-even
  return (ushort_t)(u >> 16);
}

#define GLOAD16(gp, lp)                                                        \
  __builtin_amdgcn_global_load_lds(                                            \
      (const __attribute__((address_space(1))) void*)(gp),                     \
      (__attribute__((address_space(3))) void*)(lp), 16, 0, 0)

// -------- W_ext + A_ext prep (fused): wext[OUT_][KX], aext[128][D_] bf16 ----
__global__ __launch_bounds__(256) void wprep_all_kernel(
    const float* __restrict__ W, const float* __restrict__ Bw,
    const float* __restrict__ A,
    ushort_t* __restrict__ wext, ushort_t* __restrict__ aext)
{
  const int bid = blockIdx.x;
  const int t = threadIdx.x;
  if (bid < OUT_) {
    const int o = bid;
    const float* wr = W + (size_t)o * D_ + t * 8;
    float4 v0 = *(const float4*)wr;
    float4 v1 = *(const float4*)(wr + 4);
    ushort8 wb;
    wb[0] = f2bf(v0.x); wb[1] = f2bf(v0.y); wb[2] = f2bf(v0.z); wb[3] = f2bf(v0.w);
    wb[4] = f2bf(v1.x); wb[5] = f2bf(v1.y); wb[6] = f2bf(v1.z); wb[7] = f2bf(v1.w);
    *(ushort8*)(wext + (size_t)o * KX + t * 8) = wb;
    if (t < E_ * R_) {
      const int e = t >> 4, r = t & 15;
      wext[(size_t)o * KX + D_ + t] = f2bf(Bw[((size_t)e * OUT_ + o) * R_ + r]);
    }
  } else {
    const size_t i = ((size_t)(bid - OUT_) * 256 + t) * 8;
    float4 v0 = *(const float4*)(A + i);
    float4 v1 = *(const float4*)(A + i + 4);
    ushort8 b;
    b[0] = f2bf(v0.x); b[1] = f2bf(v0.y); b[2] = f2bf(v0.z); b[3] = f2bf(v0.w);
    b[4] = f2bf(v1.x); b[5] = f2bf(v1.y); b[6] = f2bf(v1.z); b[7] = f2bf(v1.w);
    *(ushort8*)(aext + i) = b;
  }
}

// ---- FUSED router + h GEMM + x convert, HIGH-TLP variant -------------------
// BM=16 rows/block, 256 thr (4 waves), grid 1024 -> 4096 waves = 16 waves/CU
// (2x the r10 structure's 2048-wave cap; LDS 37KB -> 4 blocks/CU, exact fill).
// Same r6/r10 loop skeleton: stageA (gload_lds, swizzled src) + putX (cvt +
// swizzled ds_write + xext-core gstore) + __syncthreads. Wave w owns h-cols
// w*32..w*32+31; af from 2KB X-tile (rows=lr); 4 MFMA/tile; acc[2].
// Logits: 4 cols/thread fp32 partials + fp64 16-lane tree + argmax -> esel.
// MFMA inputs bit-identical to r10 => h bytes identical => absmax unchanged.
#define HG_NKT (D_ / 64)     // 32 K-tiles
#define HR_BUF 18432         // 2KB X + 16KB A per buffer

__global__ __launch_bounds__(256) void hrouter3_kernel(
    const float* __restrict__ x,       // [M_][D_] fp32
    const float* __restrict__ rW,      // [E_][D_] fp32
    const ushort_t* __restrict__ Ae,   // [128][D_] bf16
    ushort_t* __restrict__ xext)       // writes all KX cols
{
  __shared__ __attribute__((aligned(16))) char lds[2 * HR_BUF];
  __shared__ double lsum[16][E_];
  __shared__ int esel[16];

  const int t = threadIdx.x;
  const int lane = t & 63, w = t >> 6;        // wave = col quarter (32 cols)
  const int lr = lane & 15, lg = lane >> 4;

  const int bm = blockIdx.x;                   // 1024 blocks x 16 rows
  const size_t row0 = (size_t)bm * 16;

  const int srow = t >> 4;                     // staging row 0..15
  const int sc   = t & 15;                     // 4-float col chunk 0..15

  // stage Ae tile TT (128x64 bf16) into buf TT&1 (proven r10 pattern)
  auto stageA = [&](int TT) {
    char* dst = lds + (TT & 1) * HR_BUF + 2048;
    #pragma unroll
    for (int g = 0; g < 4; ++g) {
      const int c = g * 256 + t;
      const int row = c >> 3, slotx = (c & 7) ^ (row & 7);
      GLOAD16(Ae + (size_t)row * D_ + TT * 64 + slotx * 8, dst + c * 16);
    }
  };
  // cvt 4 x-floats -> bf16: swizzled ds_write (8B) + xext core gstore (8B)
  auto putX = [&](int TT, const float4& a) {
    ushort4 xb;
    xb.x = f2bf(a.x); xb.y = f2bf(a.y); xb.z = f2bf(a.z); xb.w = f2bf(a.w);
    char* Xb = lds + (TT & 1) * HR_BUF;
    const int cb = (((sc >> 1) ^ (srow & 7)) << 4) + (sc & 1) * 8;
    *(ushort4*)(Xb + srow * 128 + cb) = xb;
    *(ushort4*)(xext + (row0 + srow) * KX + TT * 64 + sc * 4) = xb;
  };

  float la[E_] = {};
  f32x4 acc[2] = {};

  const float* xrow = x + (row0 + srow) * D_;

  float4 cur = *(const float4*)(xrow + sc * 4);
  stageA(0);
  putX(0, cur);
  __syncthreads();

  for (int T = 0; T < HG_NKT; ++T) {
    float4 nxt;
    const bool more = (T + 1 < HG_NKT);
    if (more) {
      nxt = *(const float4*)(xrow + (T + 1) * 64 + sc * 4);
      stageA(T + 1);
    }
    // router logit partials on tile T (rW slices L1-broadcast across rows)
    #pragma unroll
    for (int e = 0; e < E_; ++e) {
      const float4 wv = *(const float4*)(rW + (size_t)e * D_ + T * 64 + sc * 4);
      la[e] += cur.x * wv.x + cur.y * wv.y + cur.z * wv.z + cur.w * wv.w;
    }
    char* Xb = lds + (T & 1) * HR_BUF;
    char* Ab = Xb + 2048;
    bf16x8 af[2], bfr[2][2];
    #pragma unroll
    for (int kk = 0; kk < 2; ++kk)
      af[kk] = *(const bf16x8*)(Xb + lr * 128 + ((kk * 64 + lg * 16) ^ ((lr & 7) << 4)));
    #pragma unroll
    for (int nj = 0; nj < 2; ++nj) {
      const int Rc = w * 32 + nj * 16 + lr;
      #pragma unroll
      for (int kk = 0; kk < 2; ++kk)
        bfr[nj][kk] = *(const bf16x8*)(Ab + Rc * 128 + ((kk * 64 + lg * 16) ^ ((Rc & 7) << 4)));
    }
    #pragma unroll
    for (int nj = 0; nj < 2; ++nj)
      #pragma unroll
      for (int kk = 0; kk < 2; ++kk)
        acc[nj] = __builtin_amdgcn_mfma_f32_16x16x32_bf16(af[kk], bfr[nj][kk], acc[nj], 0, 0, 0);
    if (more) putX(T + 1, nxt);
    __syncthreads();   // full drain: vmcnt (Ae DMA) + lgkm (X ds_write)
    cur = nxt;
  }

  // router finish: fp64 tree over each row's 16 lanes -> LDS -> argmax
  {
    double s[E_];
    #pragma unroll
    for (int e = 0; e < E_; ++e) s[e] = (double)la[e];
    #pragma unroll
    for (int off = 1; off <= 8; off <<= 1)
      #pragma unroll
      for (int e = 0; e < E_; ++e) s[e] += __shfl_xor(s[e], off, 64);
    if ((lane & 15) == 0) {
      #pragma unroll
      for (int e = 0; e < E_; ++e) lsum[w * 4 + (lane >> 4)][e] = s[e];
    }
  }
  __syncthreads();
  if (t < 16) {
    double best = lsum[t][0]; int bi = 0;
    #pragma unroll
    for (int e = 1; e < E_; ++e)
      if (lsum[t][e] > best) { best = lsum[t][e]; bi = e; }  // first-max
    esel[t] = bi;
  }
  __syncthreads();

  // masked epilogue: xext[row][D_+col] = (esel[row]==col>>4) ? bf16(2*h) : 0
  int er[4];
  #pragma unroll
  for (int rr = 0; rr < 4; ++rr)
    er[rr] = esel[lg * 4 + rr];
  #pragma unroll
  for (int nj = 0; nj < 2; ++nj) {
    const int col = w * 32 + nj * 16 + lr;
    const int ecol = w * 2 + nj;               // col>>4, wave-uniform per nj
    #pragma unroll
    for (int rr = 0; rr < 4; ++rr) {
      const size_t row = row0 + lg * 4 + rr;
      ushort_t v = (er[rr] == ecol) ? f2bf(acc[nj][rr] * SCALING_F) : (ushort_t)0;
      xext[row * KX + D_ + col] = v;
    }
  }
}

// ---------------- GEMM: 256x256, symmetric 8-phase / 2-K-tile schedule ------
// (byte-identical to round 10 — isolation; r10 measured 144.6-144.8 us)
#define NKT (KX / 64)        // 34 K-tiles
#define NITER (NKT / 2)      // 17 iterations
#define NSTG (NKT * 4)       // 136 half-tile stages

__global__ __launch_bounds__(512, 2) void gemm_kernel(
    const ushort_t* __restrict__ Ag,   // [M_][KX] bf16
    const ushort_t* __restrict__ Bg,   // [OUT_][KX] bf16
    const float* __restrict__ bias,
    float* __restrict__ C)
{
  __shared__ __attribute__((aligned(16))) char lds[131072];

  const int t = threadIdx.x;
  const int lane = t & 63, w = t >> 6;
  const int wm = w >> 2, wn = w & 3;          // 2x4 wave grid; wave tile 128x64
  const int lr = lane & 15, lg = lane >> 4;
  const int koff = (lr & 7) << 4;             // read-side swizzle XOR (bytes)

  // XCD-bijective blockIdx swizzle (512 % 8 == 0)
  const int swz = (blockIdx.x & 7) * 64 + (blockIdx.x >> 3);
  const int bm = swz >> 3, bn = swz & 7;

  const int sg_row = t >> 3;
  const int sg_slotx = (t & 7) ^ ((t >> 3) & 7);   // pre-swizzled source slot
  const size_t aRow0 = (size_t)bm * 256;
  const size_t bRow0 = (size_t)bn * 256;

  // stage half-tile s: tile TT=s>>2, j=s&3 (0,1 = A halves; 2,3 = B halves)
  auto stage = [&](int s) {
    if (s >= NSTG) return;
    const int TT = s >> 2, j = s & 3;
    const int isB = j >> 1, half = j & 1;
    const ushort_t* src = isB ? Bg : Ag;
    const size_t gr0 = (isB ? bRow0 : aRow0) + half * 128;
    char* dst = lds + (TT & 1) * 65536 + isB * 32768 + half * 16384;
    #pragma unroll
    for (int g = 0; g < 2; ++g) {
      const int r = g * 64 + sg_row;
      GLOAD16(src + (gr0 + r) * KX + TT * 64 + sg_slotx * 8,
              dst + g * 8192 + t * 16);
    }
  };

  f32x4 acc[8][4] = {};
  bf16x8 bq[4][2];

  // prologue: tile0 {A0,A1,B0,B1} + tile1 {B0,B1}; wait tile0 landed,
  // leaving tile1's B (4 loads) in flight. (tile1's A staged at iter0 p0/p1.)
  stage(0); stage(1); stage(2); stage(3);
  stage(6); stage(7);
  asm volatile("s_waitcnt vmcnt(4)" ::: "memory");
  __builtin_amdgcn_s_barrier();

  for (int ii = 0; ii < NITER; ++ii) {
    #pragma unroll
    for (int p = 0; p < 8; ++p) {
      const int q = p & 3;
      char* Ab = lds + ((2 * ii + (p >> 2)) & 1) * 65536;
      char* Bb = Ab + 32768;
      // --- ds-load register subtile ---
      bf16x8 aq[2][2];
      if (q == 0) {
        #pragma unroll
        for (int nj = 0; nj < 4; ++nj) {
          const int R = wn * 64 + nj * 16 + lr;
          #pragma unroll
          for (int kk = 0; kk < 2; ++kk)
            bq[nj][kk] = *(const bf16x8*)(Bb + R * 128 + ((kk * 64 + lg * 16) ^ koff));
        }
      }
      #pragma unroll
      for (int i = 0; i < 2; ++i) {
        const int R = wm * 128 + (q * 2 + i) * 16 + lr;
        #pragma unroll
        for (int kk = 0; kk < 2; ++kk)
          aq[i][kk] = *(const bf16x8*)(Ab + R * 128 + ((kk * 64 + lg * 16) ^ koff));
      }
      // --- one half-tile stage per phase ---
      switch (p) {
        case 0: stage(4 * (2 * ii + 1) + 0); break;
        case 1: stage(4 * (2 * ii + 1) + 1); break;
        case 2: stage(4 * (2 * ii + 2) + 2); break;
        case 3: stage(4 * (2 * ii + 2) + 3); break;
        case 4: stage(4 * (2 * ii + 2) + 0); break;
        case 5: stage(4 * (2 * ii + 2) + 1); break;
        case 6: stage(4 * (2 * ii + 3) + 2); break;
        case 7: stage(4 * (2 * ii + 3) + 3); break;
      }
      if (q == 0) asm volatile("s_waitcnt lgkmcnt(8)" ::: "memory");
      __builtin_amdgcn_s_barrier();
      asm volatile("s_waitcnt lgkmcnt(0)" ::: "memory");
      // --- MFMA cluster: one C-quadrant (2 m-frags x 4 n-frags) x K=64 ---
      __builtin_amdgcn_s_setprio(1);
      #pragma unroll
      for (int i = 0; i < 2; ++i)
        #pragma unroll
        for (int nj = 0; nj < 4; ++nj)
          #pragma unroll
          for (int kk = 0; kk < 2; ++kk)
            acc[q * 2 + i][nj] = __builtin_amdgcn_mfma_f32_16x16x32_bf16(
                aq[i][kk], bq[nj][kk], acc[q * 2 + i][nj], 0, 0, 0);
      __builtin_amdgcn_s_setprio(0);
      if (p == 3 || p == 7) {
        if (ii == NITER - 1) asm volatile("s_waitcnt vmcnt(0)" ::: "memory");
        else                 asm volatile("s_waitcnt vmcnt(4)" ::: "memory");
      }
      __builtin_amdgcn_s_barrier();
    }
  }

  // epilogue: C = acc + bias ; C/D layout col=lane&15, row=(lane>>4)*4+reg
  #pragma unroll
  for (int nj = 0; nj < 4; ++nj) {
    const int col = bn * 256 + wn * 64 + nj * 16 + lr;
    const float bv = bias[col];
    #pragma unroll
    for (int mi = 0; mi < 8; ++mi) {
      const int row0 = bm * 256 + wm * 128 + mi * 16 + lg * 4;
      #pragma unroll
      for (int rr = 0; rr < 4; ++rr)
        C[(size_t)(row0 + rr) * OUT_ + col] = acc[mi][nj][rr] + bv;
    }
  }
}

extern "C" void kernel_launch(void* const* d_in, const int* in_sizes, int n_in,
                              void* d_out, int out_size, void* d_ws, size_t ws_size,
                              hipStream_t stream) {
  const float* x  = (const float*)d_in[0];   // [4,4096,2048]
  const float* Wb = (const float*)d_in[1];   // [2048,2048]
  const float* bb = (const float*)d_in[2];   // [2048]
  const float* rW = (const float*)d_in[3];   // [8,2048]
  const float* A  = (const float*)d_in[4];   // [8,16,2048]
  const float* Bw = (const float*)d_in[5];   // [8,2048,16]
  float* out = (float*)d_out;                // [4,4096,2048] fp32

  ushort_t* xext = (ushort_t*)d_ws;                                   // M_ x KX bf16
  ushort_t* wext = (ushort_t*)((char*)d_ws + (size_t)M_ * KX * 2);    // OUT_ x KX bf16
  ushort_t* aext = (ushort_t*)((char*)d_ws + (size_t)M_ * KX * 2
                                           + (size_t)OUT_ * KX * 2);  // 128 x D_ bf16

  wprep_all_kernel<<<OUT_ + (E_ * R_ * D_) / (256 * 8), 256, 0, stream>>>(Wb, Bw, A, wext, aext);
  hrouter3_kernel<<<M_ / 16, 256, 0, stream>>>(x, rW, aext, xext);
  gemm_kernel<<<(M_ / 256) * (OUT_ / 256), 512, 0, stream>>>(xext, wext, bb, out);
}